// Round 8
// baseline (408.370 us; speedup 1.0000x reference)
//
#include <hip/hip_runtime.h>
#include <hip/hip_bf16.h>

// y = (fq_per_token(x) @ fq_per_channel(w)^T) + b
// Exact int8 factorization: y[m,n] = sx[m]*sw[n]*dot_i32(qx[m,:],qw[n,:]) + b[n]

#define K_DIM 4096
#define N_DIM 4096
#define NT (K_DIM / 128)   // 32 K-tiles of 128 bytes

typedef int v4i  __attribute__((ext_vector_type(4)));
typedef int v16i __attribute__((ext_vector_type(16)));

__device__ __forceinline__ void cp16(void* lds, const void* g) {
    __builtin_amdgcn_global_load_lds(
        (const __attribute__((address_space(1))) void*)g,
        (__attribute__((address_space(3))) void*)lds, 16, 0, 0);
}

// ---------------------------------------------------------------------------
// Per-row symmetric int8 fake-quant, x and w merged into one grid. UNCHANGED.
// ---------------------------------------------------------------------------
__global__ __launch_bounds__(256) void quant_rows_kernel(
    const float* __restrict__ x, const float* __restrict__ w, int M,
    char* __restrict__ qx, char* __restrict__ qw,
    float* __restrict__ sx, float* __restrict__ sw) {
    const int blk = blockIdx.x;
    const bool is_x = blk < M;
    const int row = is_x ? blk : blk - M;
    const float* rp = (is_x ? x : w) + (size_t)row * 4096;
    char* qdst = is_x ? qx : qw;
    float* sdst = is_x ? sx : sw;

    const int tid = threadIdx.x;

    float4 v[4];
#pragma unroll
    for (int i = 0; i < 4; ++i)
        v[i] = *(const float4*)(rp + 4 * (tid + 256 * i));

    float m = 0.0f;
#pragma unroll
    for (int i = 0; i < 4; ++i) {
        m = fmaxf(m, fmaxf(fmaxf(fabsf(v[i].x), fabsf(v[i].y)),
                           fmaxf(fabsf(v[i].z), fabsf(v[i].w))));
    }
#pragma unroll
    for (int off = 32; off > 0; off >>= 1)
        m = fmaxf(m, __shfl_down(m, off));

    __shared__ float red[4];
    if ((tid & 63) == 0) red[tid >> 6] = m;
    __syncthreads();
    const float amax = fmaxf(fmaxf(red[0], red[1]), fmaxf(red[2], red[3]));
    const float scale = fmaxf(amax / 127.0f, 1e-8f);
    const float qs = 1.0f / scale;

    int* qout = (int*)(qdst + (size_t)row * 4096);
#pragma unroll
    for (int i = 0; i < 4; ++i) {
        int q0 = (int)fminf(fmaxf(rintf(v[i].x * qs), -128.0f), 127.0f);
        int q1 = (int)fminf(fmaxf(rintf(v[i].y * qs), -128.0f), 127.0f);
        int q2 = (int)fminf(fmaxf(rintf(v[i].z * qs), -128.0f), 127.0f);
        int q3 = (int)fminf(fmaxf(rintf(v[i].w * qs), -128.0f), 127.0f);
        qout[tid + 256 * i] =
            (q0 & 255) | ((q1 & 255) << 8) | ((q2 & 255) << 16) | ((q3 & 255) << 24);
    }
    if (tid == 0) sdst[row] = scale;
}

// ---------------------------------------------------------------------------
// int8 GEMM, 256x256 tile, 8 waves (2M x 4N), BK = 128 bytes, free-run loop
// (1 barrier per K-tile = best config, round 5: 133.5us). Round-7's
// 2-blocks/CU regressed (150.7us) -> reverted.
//
// Round-8 change (single variable vs round 5): mfma_i32_32x32x32_i8.
//   - ubench 4404 vs 3944 TOPS -> per-tile MFMA floor 2611 -> 2342 cy.
//   - 32 instead of 64 MFMA instrs/wave/tile: halves the wave's MFMA issue
//     occupancy, freeing issue slots for ds_read issue during the MFMA
//     window (remaining suspect for the measured LDS/MFMA serialization:
//     rounds 1-7 all land ~5000 cy/tile = 1150 LDS + 1306 MFMA per k-step,
//     serial, regardless of barrier/schedule structure).
//   - A/B layout: row = lane&31, k = (lane>>5)*16 + byte — direct extension
//     of the harness-proven 16x16x64 mapping. C/D: col = lane&31,
//     row = (reg&3) + 8*(reg>>2) + 4*(lane>>5)  [guide-verified m74/m101].
//   - Per wave-tile (128x64): 4 m-subtiles x 2 n-subtiles, acc = 8 x v16i
//     (128 regs, same as before). Per 32B k-step: 6 ds_read_b128 + 8 MFMA;
//     4 k-steps per 128B tile -> 24 reads + 32 MFMA per wave per tile.
//
// Staging/swizzle identical to round 5 (proven, 0 conflicts): LDS 16B chunk
// (row r, pos p) holds global chunk p ^ (r&7); fragment read for global
// chunk g = 2*ks + (lane>>5) uses pos = g ^ (r&7) -> every 8-lane b128
// service group hits 8 distinct bank-groups (pos = c^{0..7}).
//
// Loop: [BAR] stage A,B(t+1)->par^1 (8 cp16) ; 4 x {6 ds_read ; 8 MFMA} ;
// vmcnt(0) ; [BAR].  RAW/WAR/drain arguments unchanged from round 5.
// ---------------------------------------------------------------------------
__global__ __launch_bounds__(512, 2) void gemm_i8_kernel(
    const char* __restrict__ qx, const char* __restrict__ qw,
    const float* __restrict__ sx, const float* __restrict__ sw,
    const float* __restrict__ bias, float* __restrict__ y) {

    __shared__ __align__(16) char lds[131072];

    const int tid  = threadIdx.x;
    const int wave = tid >> 6;
    const int lane = tid & 63;
    const int l31  = lane & 31;   // MFMA row/col index
    const int hi   = lane >> 5;   // k-subchunk select / C-row offset 4*hi
    const int wm   = wave >> 2;   // wave tile m (0..1) -> rows wm*128..+127
    const int wn   = wave & 3;    // wave tile n (0..3) -> cols wn*64..+63

    const int bm = blockIdx.y;
    const int bn = blockIdx.x;

    // staging: thread t handles 16B chunks t and t+512 of each 128-row half
    // (wave-contiguous LDS dest for global_load_lds); global source
    // pre-swizzled so LDS chunk (r, p) holds global k-chunk p ^ (r&7).
    const int ci0 = tid,       r0s = ci0 >> 3, c0s = (ci0 & 7) ^ (r0s & 7);
    const int ci1 = tid + 512, r1s = ci1 >> 3, c1s = (ci1 & 7) ^ (r1s & 7);
    const char* aS0 = qx + (size_t)(bm * 256 + r0s) * K_DIM + c0s * 16;
    const char* aS1 = qx + (size_t)(bm * 256 + r1s) * K_DIM + c1s * 16;
    const char* bS0 = qw + (size_t)(bn * 256 + r0s) * K_DIM + c0s * 16;
    const char* bS1 = qw + (size_t)(bn * 256 + r1s) * K_DIM + c1s * 16;
    const int ldsC0 = ci0 * 16, ldsC1 = ci1 * 16;

#define SLOT_A(par, h) ((par) * 65536 + (h) * 16384)
#define SLOT_B(par, h) ((par) * 65536 + 32768 + (h) * 16384)
#define STAGE_A(par, h, t) do {                                              \
    cp16(lds + SLOT_A(par, h) + ldsC0,                                       \
         aS0 + (size_t)(h) * 128 * K_DIM + (size_t)(t) * 128);               \
    cp16(lds + SLOT_A(par, h) + ldsC1,                                       \
         aS1 + (size_t)(h) * 128 * K_DIM + (size_t)(t) * 128); } while (0)
#define STAGE_B(par, h, t) do {                                              \
    cp16(lds + SLOT_B(par, h) + ldsC0,                                       \
         bS0 + (size_t)(h) * 128 * K_DIM + (size_t)(t) * 128);               \
    cp16(lds + SLOT_B(par, h) + ldsC1,                                       \
         bS1 + (size_t)(h) * 128 * K_DIM + (size_t)(t) * 128); } while (0)

#define BAR()   __builtin_amdgcn_s_barrier()
#define FENCE() asm volatile("" ::: "memory")

    // fragment read bases (within parity region); per k-step ks the global
    // 16B chunk is g = 2*ks + hi, read at swizzled pos g ^ (r&7).
    const int pxor = (l31 & 7) * 16;                    // row-dependent XOR
    const int aRd  = wm * 16384 + l31 * 128;            // + mt*4096
    const int bRd  = 32768 + wn * 8192 + l31 * 128;     // + nt*4096

    v16i acc[4][2] = {};

    // ---- prologue: stage tile 0 fully, drain, barrier
    STAGE_A(0, 0, 0); STAGE_A(0, 1, 0);
    STAGE_B(0, 0, 0); STAGE_B(0, 1, 0);
    asm volatile("s_waitcnt vmcnt(0)" ::: "memory");
    BAR(); FENCE();

    for (int t = 0; t < NT; ++t) {
        const int par  = t & 1;
        const int base = par << 16;

        // stage next tile into the other parity; issued first so HBM
        // latency hides under the whole tile's compute.
        if (t + 1 < NT) {
            STAGE_A(par ^ 1, 0, t + 1); STAGE_A(par ^ 1, 1, t + 1);
            STAGE_B(par ^ 1, 0, t + 1); STAGE_B(par ^ 1, 1, t + 1);
        }

        // free-run: 4 k-steps of {6 ds_read_b128 ; 8 MFMA}; compiler emits
        // counted lgkmcnt so MFMAs start as soon as operands land.
#pragma unroll
        for (int ks = 0; ks < 4; ++ks) {
            const int ch = (((ks << 1) | hi) << 4) ^ pxor;  // pos*16
            v4i a[4], b[2];
#pragma unroll
            for (int mt = 0; mt < 4; ++mt)
                a[mt] = *(const v4i*)(lds + base + aRd + mt * 4096 + ch);
#pragma unroll
            for (int nt = 0; nt < 2; ++nt)
                b[nt] = *(const v4i*)(lds + base + bRd + nt * 4096 + ch);
            __builtin_amdgcn_s_setprio(1);
#pragma unroll
            for (int mt = 0; mt < 4; ++mt)
#pragma unroll
                for (int nt = 0; nt < 2; ++nt)
                    acc[mt][nt] = __builtin_amdgcn_mfma_i32_32x32x32_i8(
                        a[mt], b[nt], acc[mt][nt], 0, 0, 0);
            __builtin_amdgcn_s_setprio(0);
        }

        // drain t+1's stages (issued ~a full tile ago -> ~free), then the
        // single per-tile barrier.
        asm volatile("s_waitcnt vmcnt(0)" ::: "memory");
        BAR(); FENCE();
    }

    // ---- epilogue. C/D (32x32): col = lane&31, row = (r&3)+8*(r>>2)+4*hi.
    const int m_base = bm * 256 + wm * 128;
    const int n_base = bn * 256 + wn * 64;

#pragma unroll
    for (int nt = 0; nt < 2; ++nt) {
        const int col = n_base + nt * 32 + l31;
        const float swv = sw[col];
        const float bv  = bias[col];
#pragma unroll
        for (int mt = 0; mt < 4; ++mt) {
#pragma unroll
            for (int rq = 0; rq < 4; ++rq) {
                const int row0 = m_base + mt * 32 + rq * 8 + hi * 4;
                const float4 s4 = *(const float4*)(sx + row0);
                const float sv[4] = {s4.x, s4.y, s4.z, s4.w};
#pragma unroll
                for (int i = 0; i < 4; ++i) {
                    y[(size_t)(row0 + i) * N_DIM + col] =
                        (float)acc[mt][nt][rq * 4 + i] * sv[i] * swv + bv;
                }
            }
        }
    }
#undef SLOT_A
#undef SLOT_B
#undef STAGE_A
#undef STAGE_B
#undef BAR
#undef FENCE
}

extern "C" void kernel_launch(void* const* d_in, const int* in_sizes, int n_in,
                              void* d_out, int out_size, void* d_ws, size_t ws_size,
                              hipStream_t stream) {
    const float* x = (const float*)d_in[0];   // [B*S, 4096] = [8192, 4096]
    const float* w = (const float*)d_in[1];   // [4096, 4096]
    const float* b = (const float*)d_in[2];   // [4096]
    float* y = (float*)d_out;                 // [8192, 4096]

    const int M = in_sizes[0] / K_DIM;        // 8192
    const int O = in_sizes[1] / K_DIM;        // 4096

    // Workspace layout
    char* qx = (char*)d_ws;                           // M*4096 int8
    char* qw = qx + (size_t)M * K_DIM;                // O*4096 int8
    float* sx = (float*)(qw + (size_t)O * K_DIM);     // M floats
    float* sw = sx + M;                               // O floats

    quant_rows_kernel<<<M + O, 256, 0, stream>>>(x, w, M, qx, qw, sx, sw);

    dim3 grid(N_DIM / 256, M / 256);                  // (16, 32) = 512 blocks
    gemm_i8_kernel<<<grid, 512, 0, stream>>>(qx, qw, sx, sw, b, y);
}